// Round 6
// baseline (186.616 us; speedup 1.0000x reference)
//
#include <hip/hip_runtime.h>
#include <math.h>

#define T_TOKENS 8192
#define HID 7168
#define NEXP 256
#define TOPK 8
#define TOPKG 4
#define RSCALE 2.5f
#define BM 128
#define KT 32
#define NCHUNK_ALL (HID / KT)          // 224 k-chunks total
#define PANEL_F16 (NEXP * 64)          // f16 elements per chunk panel (32 KB)

#define F16_MIN_NORMAL 6.103515625e-05f
#define LO_SCALE 4096.0f
#define LO_INV   (1.0f / 4096.0f)

typedef _Float16 f16;
typedef f16 f16x8 __attribute__((ext_vector_type(8)));
typedef float f32x4 __attribute__((ext_vector_type(4)));

#define VMWAIT(n) asm volatile("s_waitcnt vmcnt(" #n ")" ::: "memory")
#define LGKM0     asm volatile("s_waitcnt lgkmcnt(0)" ::: "memory")

// swizzled f16 index within a [rows][64]-f16 plane; c in [0,8) (c<4 hi, c>=4 lo)
__device__ __forceinline__ int sidx(int row, int c) {
    return row * 64 + ((c ^ (row & 7)) << 3);
}

__device__ __forceinline__ void split_f16(float x, f16& h, f16& l) {
    h = (f16)x;
    float hf = (float)h;
    if (fabsf(hf) < F16_MIN_NORMAL) { h = (f16)0.0f; hf = 0.0f; }
    l = (f16)((x - hf) * LO_SCALE);
}

__device__ __forceinline__ void gload16(const void* g, void* l) {
    __builtin_amdgcn_global_load_lds(
        (const __attribute__((address_space(1))) unsigned int*)g,
        (__attribute__((address_space(3))) unsigned int*)l, 16, 0, 0);
}

// W fp32 -> swizzled f16 hi/lo chunk panels: Wp[t][row][swz-pos], t = k-chunk.
__global__ __launch_bounds__(256) void convert_w(
    const float* __restrict__ W, f16* __restrict__ Wp)
{
    const int idx = blockIdx.x * 256 + threadIdx.x;
    const int c = idx & 3;
    const int r = (idx >> 2) & 255;
    const int t = idx >> 10;

    const float* src = W + (size_t)r * HID + t * KT + c * 8;
    float4 x0 = *(const float4*)src;
    float4 x1 = *(const float4*)(src + 4);
    const float xs[8] = {x0.x, x0.y, x0.z, x0.w, x1.x, x1.y, x1.z, x1.w};
    f16x8 h, l;
#pragma unroll
    for (int j = 0; j < 8; ++j) {
        f16 hh, ll;
        split_f16(xs[j], hh, ll);
        h[j] = hh; l[j] = ll;
    }
    f16* prow = Wp + (size_t)t * PANEL_F16 + r * 64;
    *(f16x8*)&prow[(( c      ^ (r & 7)) << 3)] = h;
    *(f16x8*)&prow[(((4 + c) ^ (r & 7)) << 3)] = l;
}

// C[t][e] = sum_k A[t][k]*W[e][k] via 3-term f16 split MFMA (scaled residuals).
// 4-phase-per-chunk schedule with counted vmcnt (no full drain in main loop).
template<int NS>
__global__ __launch_bounds__(512, 2) void gemm_f16x3(
    const float* __restrict__ A,
    const f16* __restrict__ Wp,
    float* __restrict__ out0,
    float* __restrict__ partw)
{
    constexpr int NCH = (HID / NS) / KT;
    constexpr int MB  = T_TOKENS / BM;

    __shared__ f16 lA[2][BM * 64];       // 16 KB x2
    __shared__ f16 lB[2][NEXP * 64];     // 32 KB x2

    const int tid = threadIdx.x;

    const int nb = MB * NS;
    const int chunkB = nb >> 3;
    const int logical = (blockIdx.x & 7) * chunkB + (blockIdx.x >> 3);
    const int ks = logical / MB;
    const int mt = logical % MB;
    const int m0 = mt * BM;

    // A staging: row tid>>2 (0..127), 8 k's at (tid&3)*8
    const int arow = tid >> 2;
    const int ac   = tid & 3;
    const float* Ag = A + (size_t)(m0 + arow) * HID + ks * (HID / NS) + ac * 8;

    // wave geometry: 8 waves 2(M) x 4(N); wave tile 64 x 64
    const int w  = tid >> 6;
    const int l  = tid & 63;
    const int wm = w >> 2;
    const int wn = w & 3;
    const int fr = l & 15;
    const int fk = l >> 4;

    // B gload producer role: wave w, phase p covers rows grow+16p .. +7
    const int grow = 64 * (w >> 1) + 8 * (w & 1);

    f32x4 acc [4][4];
    f32x4 accm[4][4];
#pragma unroll
    for (int i = 0; i < 4; ++i)
#pragma unroll
        for (int j = 0; j < 4; ++j) {
            acc [i][j] = (f32x4){0.f, 0.f, 0.f, 0.f};
            accm[i][j] = (f32x4){0.f, 0.f, 0.f, 0.f};
        }

    float4 aR0, aR1;

    auto issueB1 = [&](int buf, int t, int p) {
        const size_t row0 = (size_t)(grow + 16 * p);
        const f16* src = Wp + (size_t)(ks * NCH + t) * PANEL_F16 + row0 * 64 + l * 8;
        gload16(src, &lB[buf][row0 * 64]);   // wave-uniform LDS base, per-lane 16B src
    };
    auto writeA = [&](int buf) {
        const float xs[8] = {aR0.x, aR0.y, aR0.z, aR0.w, aR1.x, aR1.y, aR1.z, aR1.w};
        f16x8 h, lo;
#pragma unroll
        for (int j = 0; j < 8; ++j) {
            f16 hh, ll;
            split_f16(xs[j], hh, ll);
            h[j] = hh; lo[j] = ll;
        }
        f16* LA = &lA[buf][0];
        *(f16x8*)&LA[sidx(arow, ac)]     = h;
        *(f16x8*)&LA[sidx(arow, 4 + ac)] = lo;
    };

#define MFMA_PHASE(p)                                                                   \
    {                                                                                   \
        const int brow = wn * 64 + (p) * 16 + fr;                                       \
        f16x8 bh = *(const f16x8*)&LB[sidx(brow, fk)];                                  \
        f16x8 bl = *(const f16x8*)&LB[sidx(brow, 4 + fk)];                              \
        __builtin_amdgcn_s_setprio(1);                                                  \
        _Pragma("unroll")                                                               \
        for (int mi = 0; mi < 4; ++mi) {                                                \
            acc [mi][p] = __builtin_amdgcn_mfma_f32_16x16x32_f16(ah[mi], bh, acc [mi][p], 0, 0, 0); \
            accm[mi][p] = __builtin_amdgcn_mfma_f32_16x16x32_f16(ah[mi], bl, accm[mi][p], 0, 0, 0); \
            accm[mi][p] = __builtin_amdgcn_mfma_f32_16x16x32_f16(al[mi], bh, accm[mi][p], 0, 0, 0); \
        }                                                                               \
        __builtin_amdgcn_s_setprio(0);                                                  \
    }

#define READ_A_FRAGS()                                                                  \
    _Pragma("unroll")                                                                   \
    for (int mi = 0; mi < 4; ++mi) {                                                    \
        const int row = wm * 64 + mi * 16 + fr;                                         \
        ah[mi] = *(const f16x8*)&LA[sidx(row, fk)];                                     \
        al[mi] = *(const f16x8*)&LA[sidx(row, 4 + fk)];                                 \
    }

    // ---- prologue: A(t0) regs first (so writeA waits vmcnt(4)), then 4 gloads ----
    aR0 = *(const float4*)Ag;
    aR1 = *(const float4*)(Ag + 4);
    issueB1(0, 0, 0); issueB1(0, 0, 1); issueB1(0, 0, 2); issueB1(0, 0, 3);
    writeA(0);
    LGKM0;
    __builtin_amdgcn_s_barrier();

    // ---- main loop: chunks 0 .. NCH-2, prefetching t+1 ----
    for (int t = 0; t < NCH - 1; ++t) {
        const int cur = t & 1;
        const f16* LA = &lA[cur][0];
        const f16* LB = &lB[cur][0];
        f16x8 ah[4], al[4];

        // phase 0
        issueB1(cur ^ 1, t + 1, 0);
        {
            const float* ap = Ag + (size_t)(t + 1) * KT;
            aR0 = *(const float4*)ap;
            aR1 = *(const float4*)(ap + 4);
        }
        VMWAIT(6);
        __builtin_amdgcn_s_barrier();
        READ_A_FRAGS();
        MFMA_PHASE(0);
        __builtin_amdgcn_s_barrier();

        // phase 1
        issueB1(cur ^ 1, t + 1, 1);
        VMWAIT(6);
        __builtin_amdgcn_s_barrier();
        MFMA_PHASE(1);
        __builtin_amdgcn_s_barrier();

        // phase 2
        issueB1(cur ^ 1, t + 1, 2);
        VMWAIT(6);
        __builtin_amdgcn_s_barrier();
        MFMA_PHASE(2);
        __builtin_amdgcn_s_barrier();

        // phase 3
        issueB1(cur ^ 1, t + 1, 3);
        VMWAIT(6);
        __builtin_amdgcn_s_barrier();
        MFMA_PHASE(3);
        writeA(cur ^ 1);             // reg-dep wait = vmcnt(3): leaves gB1..3 in flight
        LGKM0;
        __builtin_amdgcn_s_barrier();
    }

    // ---- epilogue chunk (t = NCH-1): drain counted ----
    {
        const int cur = (NCH - 1) & 1;
        const f16* LA = &lA[cur][0];
        const f16* LB = &lB[cur][0];
        f16x8 ah[4], al[4];

        __builtin_amdgcn_s_barrier();        // gB0 already complete (covered by writeA wait)
        READ_A_FRAGS();
        MFMA_PHASE(0);
        __builtin_amdgcn_s_barrier();

        VMWAIT(2);
        __builtin_amdgcn_s_barrier();
        MFMA_PHASE(1);
        __builtin_amdgcn_s_barrier();

        VMWAIT(1);
        __builtin_amdgcn_s_barrier();
        MFMA_PHASE(2);
        __builtin_amdgcn_s_barrier();

        VMWAIT(0);
        __builtin_amdgcn_s_barrier();
        MFMA_PHASE(3);
    }

    float* obase = (ks == 0) ? out0 : (partw + (size_t)(ks - 1) * T_TOKENS * NEXP);
#pragma unroll
    for (int mi = 0; mi < 4; ++mi) {
#pragma unroll
        for (int ni = 0; ni < 4; ++ni) {
            const int row0 = m0 + wm * 64 + mi * 16 + fk * 4;
            const int col  = wn * 64 + ni * 16 + fr;
#pragma unroll
            for (int r = 0; r < 4; ++r)
                obase[(size_t)(row0 + r) * NEXP + col] =
                    acc[mi][ni][r] + accm[mi][ni][r] * LO_INV;
        }
    }
#undef MFMA_PHASE
#undef READ_A_FRAGS
}

// 4 tokens per 256-thread block; exact reference top-k routing.
template<int NS>
__global__ __launch_bounds__(256) void route_topk(
    const float* __restrict__ part0,
    const float* __restrict__ partw,
    const float* __restrict__ bias,
    float* __restrict__ logits,
    float* __restrict__ outw,
    float* __restrict__ outi)
{
    const int t = blockIdx.x * 4 + (threadIdx.x >> 6);
    const int l = threadIdx.x & 63;

    float4 lg = *(const float4*)&part0[(size_t)t * NEXP + 4 * l];
#pragma unroll
    for (int s = 0; s + 1 < NS; ++s) {
        float4 p = *(const float4*)&partw[((size_t)s * T_TOKENS + t) * NEXP + 4 * l];
        lg.x += p.x; lg.y += p.y; lg.z += p.z; lg.w += p.w;
    }
    *(float4*)&logits[(size_t)t * NEXP + 4 * l] = lg;

    float4 bv4 = *(const float4*)&bias[4 * l];
    const float lgv[4] = {lg.x, lg.y, lg.z, lg.w};
    const float bb[4]  = {bv4.x, bv4.y, bv4.z, bv4.w};
    float s[4], c[4];
#pragma unroll
    for (int j = 0; j < 4; ++j) {
        s[j] = 1.0f / (1.0f + expf(-lgv[j]));
        c[j] = s[j] + bb[j];
    }

    float m1 = fmaxf(c[0], c[1]), n1 = fminf(c[0], c[1]);
    float m2 = fmaxf(c[2], c[3]), n2 = fminf(c[2], c[3]);
    float v1 = fmaxf(m1, m2);
    float v2 = fmaxf(fminf(m1, m2), (m1 >= m2) ? n1 : n2);
#pragma unroll
    for (int off = 1; off < 8; off <<= 1) {
        float o1 = __shfl_xor(v1, off, 64);
        float o2 = __shfl_xor(v2, off, 64);
        float nv1 = fmaxf(v1, o1);
        float nv2 = fmaxf(fminf(v1, o1), (v1 >= o1) ? v2 : o2);
        v1 = nv1; v2 = nv2;
    }
    const float gsum = v1 + v2;

    const int myg = l >> 3;
    int rank = 0;
#pragma unroll
    for (int g = 0; g < 8; ++g) {
        float gv = __shfl(gsum, g * 8, 64);
        rank += (gv > gsum) || ((gv == gsum) && (g < myg));
    }
    const bool sel = rank < TOPKG;

    float mv[4];
#pragma unroll
    for (int j = 0; j < 4; ++j) mv[j] = sel ? c[j] : 0.0f;

    float wsel[8];
    int   isel[8];
#pragma unroll
    for (int r = 0; r < TOPK; ++r) {
        float bvv = mv[0]; int bi = (l << 2);
#pragma unroll
        for (int j = 1; j < 4; ++j) {
            if (mv[j] > bvv) { bvv = mv[j]; bi = (l << 2) + j; }
        }
#pragma unroll
        for (int off = 32; off >= 1; off >>= 1) {
            float ov = __shfl_xor(bvv, off, 64);
            int   oi = __shfl_xor(bi,  off, 64);
            if (ov > bvv || (ov == bvv && oi < bi)) { bvv = ov; bi = oi; }
        }
        const int owner = bi >> 2, slot = bi & 3;
        float myv = 0.f;
#pragma unroll
        for (int j = 0; j < 4; ++j) if (j == slot) myv = s[j];
        float sv = __shfl(myv, owner, 64);
        wsel[r] = sv; isel[r] = bi;
        if (l == owner) {
#pragma unroll
            for (int j = 0; j < 4; ++j) if (j == slot) mv[j] = -1e30f;
        }
    }

    float denom = 0.f;
#pragma unroll
    for (int r = 0; r < TOPK; ++r) denom += wsel[r];
    denom += 1e-20f;

    if (l == 0) {
#pragma unroll
        for (int r = 0; r < TOPK; ++r) {
            float wn = wsel[r] / denom;
            outw[(size_t)t * TOPK + r] = wn * RSCALE;
            outi[(size_t)t * TOPK + r] = (float)isel[r];
        }
    }
}

extern "C" void kernel_launch(void* const* d_in, const int* in_sizes, int n_in,
                              void* d_out, int out_size, void* d_ws, size_t ws_size,
                              hipStream_t stream)
{
    const float* hs   = (const float*)d_in[0];
    const float* w    = (const float*)d_in[1];
    const float* bias = (const float*)d_in[2];

    float* logits = (float*)d_out;
    float* outw   = logits + (size_t)T_TOKENS * NEXP;
    float* outi   = outw   + (size_t)T_TOKENS * TOPK;

    const size_t partBytes  = (size_t)3 * T_TOKENS * NEXP * sizeof(float);      // 25.17 MB
    const size_t panelBytes = (size_t)NCHUNK_ALL * PANEL_F16 * sizeof(f16);     // 7.34 MB

    if (ws_size >= partBytes + panelBytes) {
        float* partw = (float*)d_ws;
        f16* Wp = (f16*)((char*)d_ws + partBytes);
        convert_w<<<NCHUNK_ALL * 4, 256, 0, stream>>>(w, Wp);
        gemm_f16x3<4><<<(T_TOKENS / BM) * 4, 512, 0, stream>>>(hs, Wp, logits, partw);
        route_topk<4><<<T_TOKENS / 4, 256, 0, stream>>>(logits, partw, bias, logits, outw, outi);
    } else {
        f16* Wp = (f16*)d_ws;
        convert_w<<<NCHUNK_ALL * 4, 256, 0, stream>>>(w, Wp);
        gemm_f16x3<1><<<T_TOKENS / BM, 512, 0, stream>>>(hs, Wp, logits, logits);
        route_topk<1><<<T_TOKENS / 4, 256, 0, stream>>>(logits, logits, bias, logits, outw, outi);
    }
}

// Round 7
// 144.595 us; speedup vs baseline: 1.2906x; 1.2906x over previous
//
#include <hip/hip_runtime.h>
#include <math.h>

#define T_TOKENS 8192
#define HID 7168
#define NEXP 256
#define TOPK 8
#define TOPKG 4
#define RSCALE 2.5f
#define BM 128
#define BN 128
#define KT 32
#define NCHUNK_ALL (HID / KT)          // 224 k-chunks total
#define PANEL_F16 (NEXP * 64)          // f16 elements per chunk panel (32 KB)

#define F16_MIN_NORMAL 6.103515625e-05f
#define LO_SCALE 4096.0f
#define LO_INV   (1.0f / 4096.0f)

typedef _Float16 f16;
typedef f16 f16x8 __attribute__((ext_vector_type(8)));
typedef float f32x4 __attribute__((ext_vector_type(4)));

// swizzled f16 index within a [rows][64]-f16 plane; c in [0,8) (c<4 hi, c>=4 lo)
__device__ __forceinline__ int sidx(int row, int c) {
    return row * 64 + ((c ^ (row & 7)) << 3);
}

__device__ __forceinline__ void split_f16(float x, f16& h, f16& l) {
    h = (f16)x;
    float hf = (float)h;
    if (fabsf(hf) < F16_MIN_NORMAL) { h = (f16)0.0f; hf = 0.0f; }
    l = (f16)((x - hf) * LO_SCALE);
}

__device__ __forceinline__ void gload16(const void* g, void* l) {
    __builtin_amdgcn_global_load_lds(
        (const __attribute__((address_space(1))) unsigned int*)g,
        (__attribute__((address_space(3))) unsigned int*)l, 16, 0, 0);
}

// W fp32 -> swizzled f16 hi/lo chunk panels: Wp[t][row][swz-pos], t = k-chunk.
__global__ __launch_bounds__(256) void convert_w(
    const float* __restrict__ W, f16* __restrict__ Wp)
{
    const int idx = blockIdx.x * 256 + threadIdx.x;
    const int c = idx & 3;
    const int r = (idx >> 2) & 255;
    const int t = idx >> 10;

    const float* src = W + (size_t)r * HID + t * KT + c * 8;
    float4 x0 = *(const float4*)src;
    float4 x1 = *(const float4*)(src + 4);
    const float xs[8] = {x0.x, x0.y, x0.z, x0.w, x1.x, x1.y, x1.z, x1.w};
    f16x8 h, l;
#pragma unroll
    for (int j = 0; j < 8; ++j) {
        f16 hh, ll;
        split_f16(xs[j], hh, ll);
        h[j] = hh; l[j] = ll;
    }
    f16* prow = Wp + (size_t)t * PANEL_F16 + r * 64;
    *(f16x8*)&prow[(( c      ^ (r & 7)) << 3)] = h;
    *(f16x8*)&prow[(((4 + c) ^ (r & 7)) << 3)] = l;
}

// C[t][e] = sum_k A[t][k]*W[e][k] via 3-term f16 split MFMA (scaled residuals).
// 128x128 block tile, 4 waves (2Mx2N, wave tile 64x64), 64 KB LDS -> 2 blocks/CU.
template<int NS>
__global__ __launch_bounds__(256, 2) void gemm_f16x3(
    const float* __restrict__ A,
    const f16* __restrict__ Wp,
    float* __restrict__ out0,      // slice 0 partial (= logits region)
    float* __restrict__ partw)     // slices 1..NS-1
{
    constexpr int NCH = (HID / NS) / KT;   // chunks per slice
    constexpr int MB  = T_TOKENS / BM;     // 64 m-tiles

    __shared__ f16 lA[2][BM * 64];         // 16 KB x2
    __shared__ f16 lB[2][BN * 64];         // 16 KB x2

    const int tid = threadIdx.x;

    // chunked XCD swizzle (grid = MB*2*NS, divisible by 8 -> bijective)
    const int nb = MB * 2 * NS;
    const int chunkB = nb >> 3;
    const int logical = (blockIdx.x & 7) * chunkB + (blockIdx.x >> 3);
    const int ks = logical / (MB * 2);
    const int rem = logical % (MB * 2);
    const int mt = rem >> 1;               // adjacent logicals share the A tile
    const int bn = rem & 1;
    const int m0 = mt * BM;
    const int n0 = bn * BN;

    // A staging: 256 threads; row = tid>>1 (0..127), 16 k's at (tid&1)*16
    const int arow = tid >> 1;
    const int ac   = tid & 1;
    const float* Ag = A + (size_t)(m0 + arow) * HID + ks * (HID / NS) + ac * 16;

    // wave geometry: 4 waves 2(M) x 2(N); wave tile 64 x 64
    const int w  = tid >> 6;
    const int l  = tid & 63;
    const int wm = w >> 1;
    const int wn = w & 1;
    const int fr = l & 15;
    const int fk = l >> 4;

    f32x4 acc [4][4];
    f32x4 accm[4][4];
#pragma unroll
    for (int i = 0; i < 4; ++i)
#pragma unroll
        for (int j = 0; j < 4; ++j) {
            acc [i][j] = (f32x4){0.f, 0.f, 0.f, 0.f};
            accm[i][j] = (f32x4){0.f, 0.f, 0.f, 0.f};
        }

    float4 aR0, aR1, aR2, aR3;

    auto loadA = [&](int t) {
        const float* ap = Ag + (size_t)t * KT;
        aR0 = *(const float4*)ap;
        aR1 = *(const float4*)(ap + 4);
        aR2 = *(const float4*)(ap + 8);
        aR3 = *(const float4*)(ap + 12);
    };

    // B: wave w stages rows [w*32, w*32+32) of this block's half-panel
    auto issueB = [&](int buf, int tg) {
        const f16* pan = Wp + (size_t)tg * PANEL_F16 + (size_t)(n0 + w * 32) * 64;
        f16* dst = &lB[buf][(w * 32) * 64];
#pragma unroll
        for (int i = 0; i < 4; ++i)
            gload16(pan + i * 512 + l * 8, dst + i * 512);
    };

    auto writeA = [&](int buf) {
        f16* LA = &lA[buf][0];
        const float xs[16] = {aR0.x, aR0.y, aR0.z, aR0.w, aR1.x, aR1.y, aR1.z, aR1.w,
                              aR2.x, aR2.y, aR2.z, aR2.w, aR3.x, aR3.y, aR3.z, aR3.w};
#pragma unroll
        for (int q = 0; q < 2; ++q) {
            f16x8 h, lo;
#pragma unroll
            for (int j = 0; j < 8; ++j) {
                f16 hh, ll;
                split_f16(xs[8 * q + j], hh, ll);
                h[j] = hh; lo[j] = ll;
            }
            *(f16x8*)&LA[sidx(arow, 2 * ac + q)]     = h;
            *(f16x8*)&LA[sidx(arow, 4 + 2 * ac + q)] = lo;
        }
    };

    // prologue: chunk 0
    loadA(0);
    issueB(0, ks * NCH);
    writeA(0);
    __syncthreads();

    for (int t = 0; t < NCH; ++t) {
        const int cur = t & 1;
        const bool more = (t + 1) < NCH;
        if (more) {
            loadA(t + 1);
            issueB(cur ^ 1, ks * NCH + t + 1);
        }

        const f16* LA = &lA[cur][0];
        const f16* LB = &lB[cur][0];

        f16x8 ah[4], al[4];
#pragma unroll
        for (int mi = 0; mi < 4; ++mi) {
            const int row = wm * 64 + mi * 16 + fr;
            ah[mi] = *(const f16x8*)&LA[sidx(row, fk)];
            al[mi] = *(const f16x8*)&LA[sidx(row, 4 + fk)];
        }
        __builtin_amdgcn_s_setprio(1);
#pragma unroll
        for (int ni = 0; ni < 4; ++ni) {
            const int row = wn * 64 + ni * 16 + fr;
            f16x8 bh = *(const f16x8*)&LB[sidx(row, fk)];
            f16x8 bl = *(const f16x8*)&LB[sidx(row, 4 + fk)];
#pragma unroll
            for (int mi = 0; mi < 4; ++mi) {
                acc [mi][ni] = __builtin_amdgcn_mfma_f32_16x16x32_f16(ah[mi], bh, acc [mi][ni], 0, 0, 0);
                accm[mi][ni] = __builtin_amdgcn_mfma_f32_16x16x32_f16(ah[mi], bl, accm[mi][ni], 0, 0, 0);
                accm[mi][ni] = __builtin_amdgcn_mfma_f32_16x16x32_f16(al[mi], bh, accm[mi][ni], 0, 0, 0);
            }
        }
        __builtin_amdgcn_s_setprio(0);

        if (more) writeA(cur ^ 1);
        __syncthreads();
    }

    float* obase = (ks == 0) ? out0 : (partw + (size_t)(ks - 1) * T_TOKENS * NEXP);
#pragma unroll
    for (int mi = 0; mi < 4; ++mi) {
#pragma unroll
        for (int ni = 0; ni < 4; ++ni) {
            const int row0 = m0 + wm * 64 + mi * 16 + fk * 4;
            const int col  = n0 + wn * 64 + ni * 16 + fr;
#pragma unroll
            for (int r = 0; r < 4; ++r)
                obase[(size_t)(row0 + r) * NEXP + col] =
                    acc[mi][ni][r] + accm[mi][ni][r] * LO_INV;
        }
    }
}

// 4 tokens per 256-thread block; exact reference top-k routing.
template<int NS>
__global__ __launch_bounds__(256) void route_topk(
    const float* __restrict__ part0,
    const float* __restrict__ partw,
    const float* __restrict__ bias,
    float* __restrict__ logits,
    float* __restrict__ outw,
    float* __restrict__ outi)
{
    const int t = blockIdx.x * 4 + (threadIdx.x >> 6);
    const int l = threadIdx.x & 63;

    float4 lg = *(const float4*)&part0[(size_t)t * NEXP + 4 * l];
#pragma unroll
    for (int s = 0; s + 1 < NS; ++s) {
        float4 p = *(const float4*)&partw[((size_t)s * T_TOKENS + t) * NEXP + 4 * l];
        lg.x += p.x; lg.y += p.y; lg.z += p.z; lg.w += p.w;
    }
    *(float4*)&logits[(size_t)t * NEXP + 4 * l] = lg;

    float4 bv4 = *(const float4*)&bias[4 * l];
    const float lgv[4] = {lg.x, lg.y, lg.z, lg.w};
    const float bb[4]  = {bv4.x, bv4.y, bv4.z, bv4.w};
    float s[4], c[4];
#pragma unroll
    for (int j = 0; j < 4; ++j) {
        s[j] = 1.0f / (1.0f + expf(-lgv[j]));
        c[j] = s[j] + bb[j];
    }

    float m1 = fmaxf(c[0], c[1]), n1 = fminf(c[0], c[1]);
    float m2 = fmaxf(c[2], c[3]), n2 = fminf(c[2], c[3]);
    float v1 = fmaxf(m1, m2);
    float v2 = fmaxf(fminf(m1, m2), (m1 >= m2) ? n1 : n2);
#pragma unroll
    for (int off = 1; off < 8; off <<= 1) {
        float o1 = __shfl_xor(v1, off, 64);
        float o2 = __shfl_xor(v2, off, 64);
        float nv1 = fmaxf(v1, o1);
        float nv2 = fmaxf(fminf(v1, o1), (v1 >= o1) ? v2 : o2);
        v1 = nv1; v2 = nv2;
    }
    const float gsum = v1 + v2;

    const int myg = l >> 3;
    int rank = 0;
#pragma unroll
    for (int g = 0; g < 8; ++g) {
        float gv = __shfl(gsum, g * 8, 64);
        rank += (gv > gsum) || ((gv == gsum) && (g < myg));
    }
    const bool sel = rank < TOPKG;

    float mv[4];
#pragma unroll
    for (int j = 0; j < 4; ++j) mv[j] = sel ? c[j] : 0.0f;

    float wsel[8];
    int   isel[8];
#pragma unroll
    for (int r = 0; r < TOPK; ++r) {
        float bvv = mv[0]; int bi = (l << 2);
#pragma unroll
        for (int j = 1; j < 4; ++j) {
            if (mv[j] > bvv) { bvv = mv[j]; bi = (l << 2) + j; }
        }
#pragma unroll
        for (int off = 32; off >= 1; off >>= 1) {
            float ov = __shfl_xor(bvv, off, 64);
            int   oi = __shfl_xor(bi,  off, 64);
            if (ov > bvv || (ov == bvv && oi < bi)) { bvv = ov; bi = oi; }
        }
        const int owner = bi >> 2, slot = bi & 3;
        float myv = 0.f;
#pragma unroll
        for (int j = 0; j < 4; ++j) if (j == slot) myv = s[j];
        float sv = __shfl(myv, owner, 64);
        wsel[r] = sv; isel[r] = bi;
        if (l == owner) {
#pragma unroll
            for (int j = 0; j < 4; ++j) if (j == slot) mv[j] = -1e30f;
        }
    }

    float denom = 0.f;
#pragma unroll
    for (int r = 0; r < TOPK; ++r) denom += wsel[r];
    denom += 1e-20f;

    if (l == 0) {
#pragma unroll
        for (int r = 0; r < TOPK; ++r) {
            float wn = wsel[r] / denom;
            outw[(size_t)t * TOPK + r] = wn * RSCALE;
            outi[(size_t)t * TOPK + r] = (float)isel[r];
        }
    }
}

extern "C" void kernel_launch(void* const* d_in, const int* in_sizes, int n_in,
                              void* d_out, int out_size, void* d_ws, size_t ws_size,
                              hipStream_t stream)
{
    const float* hs   = (const float*)d_in[0];
    const float* w    = (const float*)d_in[1];
    const float* bias = (const float*)d_in[2];

    float* logits = (float*)d_out;
    float* outw   = logits + (size_t)T_TOKENS * NEXP;
    float* outi   = outw   + (size_t)T_TOKENS * TOPK;

    const size_t partBytes  = (size_t)3 * T_TOKENS * NEXP * sizeof(float);      // 25.17 MB
    const size_t panelBytes = (size_t)NCHUNK_ALL * PANEL_F16 * sizeof(f16);     // 7.34 MB

    if (ws_size >= partBytes + panelBytes) {
        float* partw = (float*)d_ws;
        f16* Wp = (f16*)((char*)d_ws + partBytes);
        convert_w<<<NCHUNK_ALL * 4, 256, 0, stream>>>(w, Wp);
        gemm_f16x3<4><<<(T_TOKENS / BM) * 2 * 4, 256, 0, stream>>>(hs, Wp, logits, partw);
        route_topk<4><<<T_TOKENS / 4, 256, 0, stream>>>(logits, partw, bias, logits, outw, outi);
    } else {
        f16* Wp = (f16*)d_ws;
        convert_w<<<NCHUNK_ALL * 4, 256, 0, stream>>>(w, Wp);
        gemm_f16x3<1><<<(T_TOKENS / BM) * 2, 256, 0, stream>>>(hs, Wp, logits, logits);
        route_topk<1><<<T_TOKENS / 4, 256, 0, stream>>>(logits, logits, bias, logits, outw, outi);
    }
}